// Round 13
// baseline (253.106 us; speedup 1.0000x reference)
//
#include <hip/hip_runtime.h>
#include <hip/hip_cooperative_groups.h>
#include <stdint.h>

namespace cg = cooperative_groups;

#define NPTS 4096
#define SENT NPTS
#define MAXSP 512
#define ECAP 65536         // edge capacity per batch (pairs; ~8x margin)

typedef unsigned long long ull;

// ---------------- LDS union-find (union-by-min: root = component min) -------
__device__ __forceinline__ int find_lds(int* p, int x){
  while (true){
    int px = p[x];
    if (px == x) return x;
    int ppx = p[px];
    if (ppx == px) return px;
    p[x] = ppx;            // path halving (benign race; links only decrease)
    x = ppx;
  }
}

__device__ __forceinline__ void union_lds(int* p, int a, int b){
  a = find_lds(p, a);
  b = find_lds(p, b);
  while (a != b){
    int lo = min(a, b), hi = max(a, b);
    int old = atomicCAS(&p[hi], hi, lo);   // LDS CAS
    if (old == hi || old == lo) return;
    a = lo; b = old;                        // old = hi's true parent (< hi)
  }
}

// j>i diagonal mask for word at lane base
__device__ __forceinline__ ull trimask(ull m, int i, int base){
  if (base + 63 <= i) return 0ULL;
  if (base <= i) return m & ((~0ULL) << (i - base + 1));
  return m;
}

// ---------------- fused cooperative kernel ----------------------------------
// phase0: pack float4(x,y,z,sq) + zero ecnt      [all blocks]
// phase1: balanced triangle adjacency -> edges   [all blocks; R12 geometry]
// phase2: per-batch mega (incidence/core/UF/labels/border/finalize)
//         [blocks 0..batches-1 only, 1024 threads each]
__global__ __launch_bounds__(1024) void k_fused(const float* __restrict__ coords,
                                                float4* __restrict__ pts,
                                                uint32_t* __restrict__ edges,
                                                int* __restrict__ ecnt,
                                                int* __restrict__ out,
                                                int batches){
#pragma clang fp contract(off)
  __shared__ int par[NPTS];          // incidence -> UF parent -> A (counts)
  __shared__ int LAB[NPTS];
  __shared__ int Bb[NPTS];           // presence/ranks
  __shared__ unsigned char corea[NPTS];
  __shared__ int wtots[16];
  __shared__ int sTot, sBase, sMost;

  cg::grid_group grid = cg::this_grid();
  int bk = blockIdx.x, t = threadIdx.x;
  int wid = t >> 6, lane = t & 63;

  // ---- phase 0: prep + counter zero ----
  int gid = bk * 1024 + t;
  int npts_all = batches << 12;
  if (gid < npts_all){
    float x = coords[gid*3+0], y = coords[gid*3+1], z = coords[gid*3+2];
    // sq: round each square, then sequential adds (XLA mul + reduce, no FMA)
    float sq = ((x*x) + (y*y)) + (z*z);
    pts[gid] = make_float4(x, y, z, sq);
  }
  if (bk == 0 && t < batches) ecnt[t << 6] = 0;   // padded 256B/batch lines
  if (t == 0) sTot = 0;
  __threadfence();
  grid.sync();

  // ---- phase 1: balanced upper-triangle adjacency -> direct edge emit ----
  // d2 bit-exactly symmetric -> j>i only. Wave handles 4 low rows (i0..i0+3)
  // + 4 mirror high rows (4092-i0..): uniform ~65 k-iters. Edge order
  // nondeterministic, SET deterministic; all consumers are order-free.
  {
    int b = bk >> 5;                    // 32 blocks per batch
    int m = ((bk & 31) << 4) + wid;     // unit in [0,512)
    int i0 = m << 2;                    // low rows  (cover 0..2044+3)
    int h0 = (NPTS - 4) - i0;           // high rows (cover 2048..4095)
    const float4* pb = pts + (b << 12);
    const float EPS2 = (float)(0.06 * 0.06);   // f64 product -> f32
    float4 pL[4], pH[4];
    #pragma unroll
    for (int r = 0; r < 4; ++r){ pL[r] = pb[i0 + r]; pH[r] = pb[h0 + r]; }
    ull wl[4] = {0,0,0,0}, wh[4] = {0,0,0,0};
    int base = lane << 6;
    {
      int W = i0 >> 6;
      float4 pj = pb[(W << 6) + lane];
      for (int k = W; k < 64; ++k){
        float4 cur = pj;
        if (k + 1 < 64) pj = pb[((k + 1) << 6) + lane];   // prefetch
        #pragma unroll
        for (int r = 0; r < 4; ++r){
          // dot: ascending-k FMA chain, first product plainly rounded (XLA)
          float dot = __builtin_fmaf(pL[r].z, cur.z,
                      __builtin_fmaf(pL[r].y, cur.y, pL[r].x * cur.x));
          float d2  = __builtin_fmaf(-2.0f, dot, pL[r].w + cur.w); // ==rn(s-rn(2dot))
          ull bal = __ballot(d2 <= EPS2);
          if (lane == k) wl[r] = bal;
        }
      }
    }
    {
      int W = h0 >> 6;
      float4 pj = pb[(W << 6) + lane];
      for (int k = W; k < 64; ++k){
        float4 cur = pj;
        if (k + 1 < 64) pj = pb[((k + 1) << 6) + lane];
        #pragma unroll
        for (int r = 0; r < 4; ++r){
          float dot = __builtin_fmaf(pH[r].z, cur.z,
                      __builtin_fmaf(pH[r].y, cur.y, pH[r].x * cur.x));
          float d2  = __builtin_fmaf(-2.0f, dot, pH[r].w + cur.w);
          ull bal = __ballot(d2 <= EPS2);
          if (lane == k) wh[r] = bal;
        }
      }
    }
    #pragma unroll
    for (int r = 0; r < 4; ++r){
      wl[r] = trimask(wl[r], i0 + r, base);
      wh[r] = trimask(wh[r], h0 + r, base);
    }
    int cnt = 0;
    #pragma unroll
    for (int r = 0; r < 4; ++r) cnt += __popcll(wl[r]) + __popcll(wh[r]);
    int incl = cnt;
    #pragma unroll
    for (int off = 1; off < 64; off <<= 1){
      int y = __shfl_up(incl, off);
      if (lane >= off) incl += y;
    }
    int total = __shfl(incl, 63);
    int woff = 0;
    if (lane == 63) woff = atomicAdd(&sTot, total);
    woff = __shfl(woff, 63);
    __syncthreads();
    if (t == 0) sBase = atomicAdd(&ecnt[b << 6], sTot);   // one atomic/block
    __syncthreads();
    int pos = sBase + woff + incl - cnt;
    uint32_t* eb = edges + (size_t)b * ECAP;
    #define EMIT(mm, row) { ull e = (mm); while (e){ int bit = __builtin_ctzll(e); \
        e &= e - 1; if (pos < ECAP) eb[pos] = ((uint32_t)(row) << 12) | (uint32_t)(base + bit); ++pos; } }
    #pragma unroll
    for (int r = 0; r < 4; ++r) EMIT(wl[r], i0 + r)
    #pragma unroll
    for (int r = 0; r < 4; ++r) EMIT(wh[r], h0 + r)
    #undef EMIT
  }
  __threadfence();
  grid.sync();

  // ---- phase 2: per-batch mega ----
  if (bk >= batches) return;
  int b = bk;
  int cnt = min(ecnt[b << 6], ECAP);
  const uint32_t* eb = edges + (size_t)b * ECAP;   // ~30KB, L2/L3-resident
  for (int s = 0; s < 4; ++s){ int v = (t << 2) + s; par[v] = 0; }
  if (t == 0) sMost = -1;
  __syncthreads();
  // P1: incidence counts. deg[i] = 1 + incidence (self-pair d2 ~ 2ulp << eps^2)
  // -> core <=> incidence >= 2 (MIN_SAMPLES=3).
  for (int e = t; e < cnt; e += 1024){
    uint32_t pk = eb[e];
    atomicAdd(&par[pk >> 12], 1);
    atomicAdd(&par[pk & 4095], 1);
  }
  __syncthreads();
  // P2: core flags, then reinit par as UF identity
  for (int s = 0; s < 4; ++s){ int v = (t << 2) + s; corea[v] = (par[v] >= 2) ? 1 : 0; }
  __syncthreads();
  for (int s = 0; s < 4; ++s){ int v = (t << 2) + s; par[v] = v; }
  __syncthreads();
  // P3: union core-core edges (single pass; fixed point = component min)
  for (int e = t; e < cnt; e += 1024){
    uint32_t pk = eb[e];
    int u = pk >> 12, v = pk & 4095;
    if (corea[u] && corea[v]) union_lds(par, u, v);
  }
  __syncthreads();
  // P4: base labels (core: root; else SENT)
  for (int s = 0; s < 4; ++s){
    int v = (t << 2) + s;
    LAB[v] = corea[v] ? find_lds(par, v) : SENT;
  }
  __syncthreads();
  // P5: border relax — min core-neighbor root via the same edge list
  for (int e = t; e < cnt; e += 1024){
    uint32_t pk = eb[e];
    int u = pk >> 12, v = pk & 4095;
    int cu = corea[u], cv = corea[v];
    if (cu && !cv)      atomicMin(&LAB[v], find_lds(par, u));
    else if (cv && !cu) atomicMin(&LAB[u], find_lds(par, v));
  }
  __syncthreads();
  // P6: finalize (noise fill, compact, cap). A aliases par (UF dead now).
  int* A = par;
  for (int s = 0; s < 4; ++s){ int v = (t << 2) + s; A[v] = 0; }
  __syncthreads();
  for (int s = 0; s < 4; ++s){ int l = LAB[(t << 2) + s]; if (l < SENT) atomicAdd(&A[l], 1); }
  __syncthreads();
  for (int s = 0; s < 4; ++s){
    int v = (t << 2) + s; int c = A[v];
    if (c > 0) atomicMax(&sMost, (c << 13) | (4095 - v));   // tie -> smallest label
  }
  __syncthreads();
  int most = (sMost >= 0) ? (4095 - (sMost & 8191)) : 0;
  for (int s = 0; s < 4; ++s){ int v = (t << 2) + s; if (LAB[v] == SENT) LAB[v] = most; Bb[v] = 0; }
  __syncthreads();
  for (int s = 0; s < 4; ++s) Bb[LAB[(t << 2) + s]] = 1;
  __syncthreads();
  // presence scan: wave shfl-scan + 16 wave totals -> rank = cumsum-1
  int pv[4]; int ls = 0;
  for (int s = 0; s < 4; ++s){ pv[s] = Bb[(t << 2) + s]; ls += pv[s]; }
  int incl = ls;
  #pragma unroll
  for (int off = 1; off < 64; off <<= 1){
    int y = __shfl_up(incl, off);
    if (lane >= off) incl += y;
  }
  if (lane == 63) wtots[wid] = incl;
  __syncthreads();
  int wbase = 0, ncl = 0;
  #pragma unroll
  for (int w = 0; w < 16; ++w){
    int wt = wtots[w];
    if (w < wid) wbase += wt;
    ncl += wt;
  }
  int run = wbase + incl - ls;
  for (int s = 0; s < 4; ++s){ run += pv[s]; Bb[(t << 2) + s] = run - 1; }
  __syncthreads();
  for (int s = 0; s < 4; ++s){ int v = (t << 2) + s; LAB[v] = Bb[LAB[v]]; }
  __syncthreads();
  if (ncl > MAXSP){
    // counts2 over compacted labels (0..ncl-1)
    for (int s = 0; s < 4; ++s) A[(t << 2) + s] = 0;
    __syncthreads();
    for (int s = 0; s < 4; ++s) atomicAdd(&A[LAB[(t << 2) + s]], 1);
    __syncthreads();
    // stable (count, index) rank over PRESENT labels only; absent labels
    // (count 0) occupy the first NPTS-ncl slots of the full argsort.
    for (int v = t; v < ncl; v += 1024){
      int keyv = A[v] * NPTS + v;
      int p = 0;
      for (int u = 0; u < ncl; ++u) p += ((A[u] * NPTS + u) < keyv) ? 1 : 0;
      int full = p + (NPTS - ncl);
      Bb[v] = (full >= NPTS - MAXSP) ? (full - (NPTS - MAXSP)) : 0;
    }
    __syncthreads();
    for (int s = 0; s < 4; ++s){ int v = (t << 2) + s; LAB[v] = Bb[LAB[v]]; }
    __syncthreads();
  }
  int* og = out + (b << 12);
  for (int s = 0; s < 4; ++s){ int v = (t << 2) + s; og[v] = LAB[v]; }
}

// ---------------- launch ----------------------------------------------------
extern "C" void kernel_launch(void* const* d_in, const int* in_sizes, int n_in,
                              void* d_out, int out_size, void* d_ws, size_t ws_size,
                              hipStream_t stream){
  const float* coords = (const float*)d_in[0];
  int* out = (int*)d_out;
  int batches = in_sizes[0] / (NPTS * 3);   // 8

  char* ws = (char*)d_ws;
  size_t off = 0;
  float4* pts = (float4*)(ws + off); off += (size_t)batches * NPTS * sizeof(float4);
  int* ecnt   = (int*)(ws + off);    off += (size_t)batches * 64 * sizeof(int); // 256B/batch
  uint32_t* edges = (uint32_t*)(ws + off); off += (size_t)batches * ECAP * sizeof(uint32_t);

  // single cooperative kernel: 32 blocks/batch x 1024 threads
  void* args[] = { (void*)&coords, (void*)&pts, (void*)&edges,
                   (void*)&ecnt, (void*)&out, (void*)&batches };
  hipLaunchCooperativeKernel((const void*)k_fused, dim3(32 * batches), dim3(1024),
                             args, 0, stream);
}

// Round 15
// 66.054 us; speedup vs baseline: 3.8318x; 3.8318x over previous
//
#include <hip/hip_runtime.h>
#include <stdint.h>

#define NPTS 4096
#define SENT NPTS
#define MAXSP 512
#define ECAP 65536         // edge capacity per batch (pairs; ~8x margin)

typedef unsigned long long ull;

// ---------------- LDS union-find (union-by-min: root = component min) -------
__device__ __forceinline__ int find_lds(int* p, int x){
  while (true){
    int px = p[x];
    if (px == x) return x;
    int ppx = p[px];
    if (ppx == px) return px;
    p[x] = ppx;            // path halving (benign race; links only decrease)
    x = ppx;
  }
}

__device__ __forceinline__ void union_lds(int* p, int a, int b){
  a = find_lds(p, a);
  b = find_lds(p, b);
  while (a != b){
    int lo = min(a, b), hi = max(a, b);
    int old = atomicCAS(&p[hi], hi, lo);   // LDS CAS
    if (old == hi || old == lo) return;
    a = lo; b = old;                        // old = hi's true parent (< hi)
  }
}

// j>i diagonal mask for word at lane base
__device__ __forceinline__ ull trimask(ull m, int i, int base){
  if (base + 63 <= i) return 0ULL;
  if (base <= i) return m & ((~0ULL) << (i - base + 1));
  return m;
}

// load point g and its sq with XLA-identical rounding.
// NOTE: contract(off) pragma is LEXICALLY scoped — it must live INSIDE this
// helper; the caller's pragma does not propagate through inlining (R14 bug).
__device__ __forceinline__ float4 loadpt(const float* __restrict__ c, int g){
#pragma clang fp contract(off)
  float x = c[g*3+0], y = c[g*3+1], z = c[g*3+2];
  float sq = ((x*x) + (y*y)) + (z*z);   // round squares, sequential adds
  return make_float4(x, y, z, sq);
}

// ---------------- K1: balanced triangle adjacency -> edges + incidence ------
// d2 bit-exactly symmetric -> j>i only. Wave = 4 low rows (i0..i0+3) + 4
// mirror high rows (4092-i0..): uniform ~65 k-iters. coords read directly;
// sq computed inline (bit-identical to the old prep). Edges emitted at
// block-atomic offsets (order nondeterministic, SET deterministic); both
// endpoints' incidence counted via spread global atomics.
__global__ void k_adj(const float* __restrict__ coords,
                      uint32_t* __restrict__ edges,
                      int* __restrict__ ecnt,
                      int* __restrict__ deg){
#pragma clang fp contract(off)
  __shared__ int sTot, sBase;
  int tid  = threadIdx.x;
  int wv   = (blockIdx.x * blockDim.x + tid) >> 6;   // 4096 waves total
  int lane = tid & 63;
  int b = wv >> 9;                  // 512 waves per batch
  int m = wv & 511;
  int i0 = m << 2;                  // low rows i0..i0+3   (cover 0..2047)
  int h0 = (NPTS - 4) - i0;         // high rows h0..h0+3  (cover 2048..4095)
  const float* cb = coords + ((size_t)b << 12) * 3;
  if (tid == 0) sTot = 0;
  __syncthreads();
  const float EPS2 = (float)(0.06 * 0.06);   // f64 product -> f32
  float4 pL[4], pH[4];
  #pragma unroll
  for (int r = 0; r < 4; ++r){ pL[r] = loadpt(cb, i0 + r); pH[r] = loadpt(cb, h0 + r); }
  ull wl[4] = {0,0,0,0}, wh[4] = {0,0,0,0};
  int base = lane << 6;
  // group 0: low rows, words i0>>6 .. 63
  {
    int W = i0 >> 6;
    float4 pj = loadpt(cb, (W << 6) + lane);
    for (int k = W; k < 64; ++k){
      float4 cur = pj;
      if (k + 1 < 64) pj = loadpt(cb, ((k + 1) << 6) + lane);   // prefetch
      #pragma unroll
      for (int r = 0; r < 4; ++r){
        // dot: ascending-k FMA chain, first product plainly rounded (XLA gebp)
        float dot = __builtin_fmaf(pL[r].z, cur.z,
                    __builtin_fmaf(pL[r].y, cur.y, pL[r].x * cur.x));
        float d2  = __builtin_fmaf(-2.0f, dot, pL[r].w + cur.w); // ==rn(s-rn(2dot))
        ull bal = __ballot(d2 <= EPS2);
        if (lane == k) wl[r] = bal;
      }
    }
  }
  // group 1: high rows, words h0>>6 .. 63
  {
    int W = h0 >> 6;
    float4 pj = loadpt(cb, (W << 6) + lane);
    for (int k = W; k < 64; ++k){
      float4 cur = pj;
      if (k + 1 < 64) pj = loadpt(cb, ((k + 1) << 6) + lane);
      #pragma unroll
      for (int r = 0; r < 4; ++r){
        float dot = __builtin_fmaf(pH[r].z, cur.z,
                    __builtin_fmaf(pH[r].y, cur.y, pH[r].x * cur.x));
        float d2  = __builtin_fmaf(-2.0f, dot, pH[r].w + cur.w);
        ull bal = __ballot(d2 <= EPS2);
        if (lane == k) wh[r] = bal;
      }
    }
  }
  // keep j > i only
  #pragma unroll
  for (int r = 0; r < 4; ++r){
    wl[r] = trimask(wl[r], i0 + r, base);
    wh[r] = trimask(wh[r], h0 + r, base);
  }
  // per-lane edge count -> wave scan -> block LDS total -> one global atomic
  int cnt = 0;
  #pragma unroll
  for (int r = 0; r < 4; ++r) cnt += __popcll(wl[r]) + __popcll(wh[r]);
  int incl = cnt;
  #pragma unroll
  for (int off = 1; off < 64; off <<= 1){
    int y = __shfl_up(incl, off);
    if (lane >= off) incl += y;
  }
  int total = __shfl(incl, 63);
  int woff = 0;
  if (lane == 63) woff = atomicAdd(&sTot, total);
  woff = __shfl(woff, 63);
  __syncthreads();                      // uniform work -> no divergence hazard
  if (tid == 0) sBase = atomicAdd(&ecnt[b << 6], sTot);  // padded 256B line
  __syncthreads();
  int pos = sBase + woff + incl - cnt;
  uint32_t* eb = edges + (size_t)b * ECAP;
  int* dg = deg + (b << 12);
  #define EMIT(mm, row) { ull e = (mm); while (e){ int bit = __builtin_ctzll(e); \
      e &= e - 1; int j = base + bit; \
      if (pos < ECAP) eb[pos] = ((uint32_t)(row) << 12) | (uint32_t)j; ++pos; \
      atomicAdd(&dg[row], 1); atomicAdd(&dg[j], 1); } }
  #pragma unroll
  for (int r = 0; r < 4; ++r) EMIT(wl[r], i0 + r)
  #pragma unroll
  for (int r = 0; r < 4; ++r) EMIT(wh[r], h0 + r)
  #undef EMIT
}

// ---------------- K2: per-batch mega kernel --------------------------------
// core (from deg) -> union-find -> labels -> border relax -> finalize, all in
// LDS; edges stream twice from global (L2/L3-resident, ~30KB/batch).
// deg[i] = incidence (self excluded; self-pair d2 ~ 2ulp << eps^2 always
// adjacent), so core <=> deg >= 2 (MIN_SAMPLES=3).
__global__ __launch_bounds__(1024) void k_mega(const uint32_t* __restrict__ edges,
                                               const int* __restrict__ ecnt,
                                               const int* __restrict__ deg,
                                               int* __restrict__ out){
  __shared__ int par[NPTS];          // UF parent -> A (counts)
  __shared__ int LAB[NPTS];
  __shared__ int Bb[NPTS];           // presence/ranks
  __shared__ unsigned char corea[NPTS];
  __shared__ int wtots[16];
  __shared__ int sMost;
  int b = blockIdx.x, t = threadIdx.x;
  int wid = t >> 6, lane = t & 63;
  int cnt = min(ecnt[b << 6], ECAP);
  const uint32_t* eb = edges + (size_t)b * ECAP;
  const int* dg = deg + (b << 12);
  // P2: core flags from precomputed incidence; par = UF identity
  for (int s = 0; s < 4; ++s){
    int v = (t << 2) + s;
    corea[v] = (dg[v] >= 2) ? 1 : 0;
    par[v] = v;
  }
  if (t == 0) sMost = -1;
  __syncthreads();
  // P3: union core-core edges (single pass; fixed point = component min)
  for (int e = t; e < cnt; e += 1024){
    uint32_t pk = eb[e];
    int u = pk >> 12, v = pk & 4095;
    if (corea[u] && corea[v]) union_lds(par, u, v);
  }
  __syncthreads();
  // P4: base labels (core: root; else SENT)
  for (int s = 0; s < 4; ++s){
    int v = (t << 2) + s;
    LAB[v] = corea[v] ? find_lds(par, v) : SENT;
  }
  __syncthreads();
  // P5: border relax — min core-neighbor root via the same edge list
  for (int e = t; e < cnt; e += 1024){
    uint32_t pk = eb[e];
    int u = pk >> 12, v = pk & 4095;
    int cu = corea[u], cv = corea[v];
    if (cu && !cv)      atomicMin(&LAB[v], find_lds(par, u));
    else if (cv && !cu) atomicMin(&LAB[u], find_lds(par, v));
  }
  __syncthreads();
  // P6: finalize (noise fill, compact, cap). A aliases par (UF dead now).
  int* A = par;
  for (int s = 0; s < 4; ++s){ int v = (t << 2) + s; A[v] = 0; }
  __syncthreads();
  for (int s = 0; s < 4; ++s){ int l = LAB[(t << 2) + s]; if (l < SENT) atomicAdd(&A[l], 1); }
  __syncthreads();
  for (int s = 0; s < 4; ++s){
    int v = (t << 2) + s; int c = A[v];
    if (c > 0) atomicMax(&sMost, (c << 13) | (4095 - v));   // tie -> smallest label
  }
  __syncthreads();
  int most = (sMost >= 0) ? (4095 - (sMost & 8191)) : 0;
  for (int s = 0; s < 4; ++s){ int v = (t << 2) + s; if (LAB[v] == SENT) LAB[v] = most; Bb[v] = 0; }
  __syncthreads();
  for (int s = 0; s < 4; ++s) Bb[LAB[(t << 2) + s]] = 1;
  __syncthreads();
  // presence scan: wave shfl-scan + 16 wave totals -> rank = cumsum-1
  int pv[4]; int ls = 0;
  for (int s = 0; s < 4; ++s){ pv[s] = Bb[(t << 2) + s]; ls += pv[s]; }
  int incl = ls;
  #pragma unroll
  for (int off = 1; off < 64; off <<= 1){
    int y = __shfl_up(incl, off);
    if (lane >= off) incl += y;
  }
  if (lane == 63) wtots[wid] = incl;
  __syncthreads();
  int wbase = 0, ncl = 0;
  #pragma unroll
  for (int w = 0; w < 16; ++w){
    int wt = wtots[w];
    if (w < wid) wbase += wt;
    ncl += wt;
  }
  int run = wbase + incl - ls;
  for (int s = 0; s < 4; ++s){ run += pv[s]; Bb[(t << 2) + s] = run - 1; }
  __syncthreads();
  for (int s = 0; s < 4; ++s){ int v = (t << 2) + s; LAB[v] = Bb[LAB[v]]; }
  __syncthreads();
  if (ncl > MAXSP){
    // counts2 over compacted labels (0..ncl-1)
    for (int s = 0; s < 4; ++s) A[(t << 2) + s] = 0;
    __syncthreads();
    for (int s = 0; s < 4; ++s) atomicAdd(&A[LAB[(t << 2) + s]], 1);
    __syncthreads();
    // stable (count, index) rank over PRESENT labels only; absent labels
    // (count 0) occupy the first NPTS-ncl slots of the full argsort.
    for (int v = t; v < ncl; v += 1024){
      int keyv = A[v] * NPTS + v;
      int p = 0;
      for (int u = 0; u < ncl; ++u) p += ((A[u] * NPTS + u) < keyv) ? 1 : 0;
      int full = p + (NPTS - ncl);
      Bb[v] = (full >= NPTS - MAXSP) ? (full - (NPTS - MAXSP)) : 0;
    }
    __syncthreads();
    for (int s = 0; s < 4; ++s){ int v = (t << 2) + s; LAB[v] = Bb[LAB[v]]; }
    __syncthreads();
  }
  int* og = out + (b << 12);
  for (int s = 0; s < 4; ++s){ int v = (t << 2) + s; og[v] = LAB[v]; }
}

// ---------------- launch ----------------------------------------------------
extern "C" void kernel_launch(void* const* d_in, const int* in_sizes, int n_in,
                              void* d_out, int out_size, void* d_ws, size_t ws_size,
                              hipStream_t stream){
  const float* coords = (const float*)d_in[0];
  int* out = (int*)d_out;
  int batches = in_sizes[0] / (NPTS * 3);   // 8

  char* ws = (char*)d_ws;
  size_t off = 0;
  int* deg  = (int*)(ws + off); off += (size_t)batches * NPTS * sizeof(int);   // 128KB
  int* ecnt = (int*)(ws + off); off += (size_t)batches * 64 * sizeof(int);     // 2KB (256B/batch)
  size_t zbytes = off;                       // deg + ecnt contiguous
  uint32_t* edges = (uint32_t*)(ws + off); off += (size_t)batches * ECAP * sizeof(uint32_t);

  int npts_all = batches * NPTS;   // 32768
  // zero deg + ecnt (graph-capturable stream memset)
  hipMemsetAsync(ws, 0, zbytes, stream);
  // K1: balanced triangle adjacency (coords direct, sq inline) -> edges + deg
  //     waves = npts_all/8 = 4096; blocks = 4096*64/256 = npts_all/32
  k_adj<<<npts_all / 32, 256, 0, stream>>>(coords, edges, ecnt, deg);
  // K2: per-batch mega (core/UF/labels/border/finalize)
  k_mega<<<batches, 1024, 0, stream>>>(edges, ecnt, deg, out);
}